// Round 9
// baseline (3165.312 us; speedup 1.0000x reference)
//
#include <hip/hip_runtime.h>
#include <hip/hip_bf16.h>

#define HDIM 128

using u16 = unsigned short;
using u32 = unsigned int;
using bf16x8 = __attribute__((ext_vector_type(8))) short;
using f32x4  = __attribute__((ext_vector_type(4))) float;

// ---------- helpers ----------
__device__ __forceinline__ float bf2f(u32 b) {
  union { u32 i; float f; } x; x.i = b << 16; return x.f;
}
__device__ __forceinline__ u16 f2bf(float f) {
  union { float f; u32 i; } x; x.f = f; u32 u = x.i;
  return (u16)((u + 0x7fffu + ((u >> 16) & 1u)) >> 16);
}
__device__ __forceinline__ void unpack8(uint4 r, float* o) {
  o[0] = bf2f(r.x & 0xffffu); o[1] = bf2f(r.x >> 16);
  o[2] = bf2f(r.y & 0xffffu); o[3] = bf2f(r.y >> 16);
  o[4] = bf2f(r.z & 0xffffu); o[5] = bf2f(r.z >> 16);
  o[6] = bf2f(r.w & 0xffffu); o[7] = bf2f(r.w >> 16);
}
__device__ __forceinline__ float sigm_f(float x) {
  return __builtin_amdgcn_rcpf(1.f + __expf(-x));
}
__device__ __forceinline__ float tanh_f(float x) {
  return 2.f * __builtin_amdgcn_rcpf(1.f + __expf(-2.f * x)) - 1.f;
}

// ---------- dtype detector (flag=1 -> inputs are packed bf16) ----------
__global__ __launch_bounds__(256) void k_detect(const u32* __restrict__ probe,
                                                int* __restrict__ flag) {
  __shared__ int cnt;
  if (threadIdx.x == 0) cnt = 0;
  __syncthreads();
  int local = 0;
  for (int i = threadIdx.x; i < 1024; i += 256) {
    u32 e = (probe[i] >> 7) & 0xFF;
    if (e >= 96 && e <= 126) local++;
  }
  atomicAdd(&cnt, local);
  __syncthreads();
  if (threadIdx.x == 0) *flag = (cnt > 512) ? 1 : 0;
}

// ---------- converters ----------
__global__ __launch_bounds__(256) void k_any_to_f32(
    const void* __restrict__ src, float* __restrict__ dst, int n8,
    const int* __restrict__ flag) {
  int i = blockIdx.x * 256 + threadIdx.x;
  if (i >= n8) return;
  float t[8];
  if (*flag) {
    uint4 raw = ((const uint4*)src)[i];
    unpack8(raw, t);
  } else {
    const float4* s = ((const float4*)src) + 2 * (size_t)i;
    float4 a = s[0], b = s[1];
    t[0] = a.x; t[1] = a.y; t[2] = a.z; t[3] = a.w;
    t[4] = b.x; t[5] = b.y; t[6] = b.z; t[7] = b.w;
  }
  float4* o = ((float4*)dst) + 2 * (size_t)i;
  o[0] = make_float4(t[0], t[1], t[2], t[3]);
  o[1] = make_float4(t[4], t[5], t[6], t[7]);
}

__global__ __launch_bounds__(256) void k_any_to_bf16(
    const void* __restrict__ src, u16* __restrict__ dst, int n8,
    const int* __restrict__ flag) {
  int i = blockIdx.x * 256 + threadIdx.x;
  if (i >= n8) return;
  uint4 o;
  if (*flag) {
    o = ((const uint4*)src)[i];
  } else {
    const float4* s = ((const float4*)src) + 2 * (size_t)i;
    float4 a = s[0], b = s[1];
    o.x = (u32)f2bf(a.x) | ((u32)f2bf(a.y) << 16);
    o.y = (u32)f2bf(a.z) | ((u32)f2bf(a.w) << 16);
    o.z = (u32)f2bf(b.x) | ((u32)f2bf(b.y) << 16);
    o.w = (u32)f2bf(b.z) | ((u32)f2bf(b.w) << 16);
  }
  ((uint4*)dst)[i] = o;
}

// ---------- build transposed bf16 weights: WT[n][k], k<KX from Wih, else Whh ----------
__global__ __launch_bounds__(256) void k_build_wt(
    const void* __restrict__ Wih, const void* __restrict__ Whh, int KX, int Ktot,
    int Ncols, u16* __restrict__ WT, const int* __restrict__ flag) {
  int idx = blockIdx.x * 256 + threadIdx.x;
  int total = Ncols * Ktot;
  if (idx >= total) return;
  int n = idx / Ktot, k = idx - n * Ktot;
  const void* src = (k < KX) ? Wih : Whh;
  int kk = (k < KX) ? k : k - KX;
  size_t off = (size_t)kk * Ncols + n;
  u16 b;
  if (*flag) b = ((const u16*)src)[off];
  else       b = f2bf(((const float*)src)[off]);
  WT[(size_t)n * Ktot + k] = b;
}

// ---------- diagnostic sentinel (ws too small) ----------
__global__ __launch_bounds__(256) void k_sentinel(float* __restrict__ out,
                                                  int n, float val) {
  int i = blockIdx.x * 256 + threadIdx.x;
  if (i < n) out[i] = val;
}

// ---------- CSR build: count / scan / fill ----------
__global__ __launch_bounds__(256) void k_count(
    const int* __restrict__ key, int key_add, int E, int* __restrict__ deg) {
  int e = blockIdx.x * 256 + threadIdx.x;
  if (e < E) atomicAdd(&deg[key[e] + key_add], 1);
}

__global__ __launch_bounds__(256) void k_scan1(
    const int* __restrict__ in, int* __restrict__ inc,
    int* __restrict__ bsum, int n) {
  __shared__ int s[256];
  const int tid = threadIdx.x;
  const int b0 = blockIdx.x * 1024;
  int v[4]; int sum = 0;
#pragma unroll
  for (int j = 0; j < 4; ++j) {
    int i = b0 + tid * 4 + j;
    int x = (i < n) ? in[i] : 0;
    sum += x; v[j] = sum;
  }
  s[tid] = sum;
  __syncthreads();
  for (int d = 1; d < 256; d <<= 1) {
    int t = (tid >= d) ? s[tid - d] : 0;
    __syncthreads();
    s[tid] += t;
    __syncthreads();
  }
  int base = (tid > 0) ? s[tid - 1] : 0;
#pragma unroll
  for (int j = 0; j < 4; ++j) {
    int i = b0 + tid * 4 + j;
    if (i < n) inc[i] = base + v[j];
  }
  if (tid == 255) bsum[blockIdx.x] = s[255];
}

__global__ __launch_bounds__(256) void k_scan2(int* __restrict__ bsum, int nb) {
  __shared__ int s[256];
  const int tid = threadIdx.x;
  int x = (tid < nb) ? bsum[tid] : 0;
  s[tid] = x;
  __syncthreads();
  for (int d = 1; d < 256; d <<= 1) {
    int t = (tid >= d) ? s[tid - d] : 0;
    __syncthreads();
    s[tid] += t;
    __syncthreads();
  }
  if (tid < nb) bsum[tid] = (tid > 0) ? s[tid - 1] : 0;
}

__global__ __launch_bounds__(256) void k_scan3(
    const int* __restrict__ inc, const int* __restrict__ bsum,
    int* __restrict__ off, int* __restrict__ cursor, int n) {
  int i = blockIdx.x * 256 + threadIdx.x;
  if (i < n) {
    int v = inc[i] + bsum[i >> 10];
    off[i + 1] = v;
    int prev = (i & 1023) ? (inc[i - 1] + bsum[i >> 10]) : bsum[i >> 10];
    cursor[i] = prev;
    if (i == 0) { off[0] = 0; cursor[0] = 0; }
  }
}

__global__ __launch_bounds__(256) void k_fill(
    const int* __restrict__ key, int key_add,
    const int* __restrict__ pay, int pay_add, int E,
    int* __restrict__ cursor, int* __restrict__ vals) {
  int e = blockIdx.x * 256 + threadIdx.x;
  if (e >= E) return;
  int k = key[e] + key_add;
  int p = atomicAdd(&cursor[k], 1);
  vals[p] = pay[e] + pay_add;
}

// ---------- fused 3-layer MLP: Y = (relu(relu(X@W0+b0)@W1+b1))@W2+b2 ----------
// 128 rows/block, 256 thr (4 waves). Layers chained through XOR-swizzled LDS.
__global__ __launch_bounds__(256) void k_mlp3(
    const u16* __restrict__ X, u16* __restrict__ Y, int N,
    const u16* __restrict__ WT0, const float* __restrict__ B0,
    const u16* __restrict__ WT1, const float* __restrict__ B1,
    const u16* __restrict__ WT2, const float* __restrict__ B2) {
  __shared__ u16 xs[128 * 128];  // 32 KB
  const int tid = threadIdx.x;
  const int lane = tid & 63;
  const int w = tid >> 6;        // 0..3
  const int lr = lane & 15;
  const int hi = lane >> 4;      // 0..3
  const int lk = hi * 8;
  const int row0 = blockIdx.x * 128;

  {
    const int row = tid >> 1, half = tid & 1;
    const int grow = row0 + row;
#pragma unroll
    for (int j = 0; j < 8; ++j) {
      int g = half * 8 + j;
      uint4 v = {0, 0, 0, 0};
      if (grow < N) v = *reinterpret_cast<const uint4*>(X + (size_t)grow * HDIM + g * 8);
      ((uint4*)xs)[row * 16 + (g ^ (row & 7))] = v;
    }
  }
  __syncthreads();

  const u16* WTs[3] = {WT0, WT1, WT2};
  const float* Bs[3] = {B0, B1, B2};
#pragma unroll
  for (int layer = 0; layer < 3; ++layer) {
    f32x4 zc = {0.f, 0.f, 0.f, 0.f};
    f32x4 acc[8][2];
#pragma unroll
    for (int rt = 0; rt < 8; ++rt) { acc[rt][0] = zc; acc[rt][1] = zc; }
#pragma unroll
    for (int ks = 0; ks < 4; ++ks) {
      bf16x8 bfr[2];
#pragma unroll
      for (int t = 0; t < 2; ++t) {
        int col = w * 32 + t * 16 + lr;
        bfr[t] = *reinterpret_cast<const bf16x8*>(
            WTs[layer] + (size_t)col * HDIM + ks * 32 + lk);
      }
#pragma unroll
      for (int rt = 0; rt < 8; ++rt) {
        int row = rt * 16 + lr;
        int g = ks * 4 + hi;
        bf16x8 a = ((const bf16x8*)xs)[row * 16 + (g ^ (row & 7))];
        acc[rt][0] = __builtin_amdgcn_mfma_f32_16x16x32_bf16(a, bfr[0], acc[rt][0], 0, 0, 0);
        acc[rt][1] = __builtin_amdgcn_mfma_f32_16x16x32_bf16(a, bfr[1], acc[rt][1], 0, 0, 0);
      }
    }
    float bv[2];
    bv[0] = Bs[layer][w * 32 + lr];
    bv[1] = Bs[layer][w * 32 + 16 + lr];
    __syncthreads();
    if (layer < 2) {
#pragma unroll
      for (int rt = 0; rt < 8; ++rt)
#pragma unroll
        for (int t = 0; t < 2; ++t) {
          int col = w * 32 + t * 16 + lr;
          int g = col >> 3, cw = col & 7;
#pragma unroll
          for (int reg = 0; reg < 4; ++reg) {
            int row = rt * 16 + hi * 4 + reg;
            float v = fmaxf(acc[rt][t][reg] + bv[t], 0.f);
            xs[(row * 16 + (g ^ (row & 7))) * 8 + cw] = f2bf(v);
          }
        }
      __syncthreads();
    } else {
#pragma unroll
      for (int rt = 0; rt < 8; ++rt)
#pragma unroll
        for (int t = 0; t < 2; ++t) {
          int col = w * 32 + t * 16 + lr;
#pragma unroll
          for (int reg = 0; reg < 4; ++reg) {
            int row = row0 + rt * 16 + hi * 4 + reg;
            if (row < N) Y[(size_t)row * HDIM + col] = f2bf(acc[rt][t][reg] + bv[t]);
          }
        }
    }
  }
}

// ---------- MFMA LSTM, 32 rows/block, 512 thr (8 waves), fused CSR gather ----------
// acc[2][4] = 32 VGPR -> fits __launch_bounds__(512,8) VGPR cap of 64.
// Stage: 16 threads/row, one pass; each thread owns one 16B granule.
// LDS [X0 | X1flip | Hin], XOR-swizzled granules (g ^ (row&7)).
// Cell state kernel-private tiled [row/16][128][16] f32 (coalesced float4).
template<int HAS_X1, int OUT_F32>
__global__ __launch_bounds__(512, 8) void k_lstm4(
    const u16* __restrict__ msgs, const int* __restrict__ moff,
    const int* __restrict__ mvals,
    const u16* __restrict__ X1, int Vhalf,
    const u16* __restrict__ Hin, const float* __restrict__ Cin,
    void* __restrict__ Hout, float* __restrict__ Cout,
    const u16* __restrict__ WT, const float* __restrict__ Bias, int N) {
  const int KT = HAS_X1 ? 384 : 256;
  const int KS = KT / 32;
  const int G = KT / 8;                          // 16B granules per row (48/32)
  __shared__ u16 xs[32 * (HAS_X1 ? 384 : 256)];  // 24 or 16 KB
  const int tid = threadIdx.x;
  const int lane = tid & 63;
  const int w = tid >> 6;                        // 0..7
  const int lr = lane & 15;
  const int hi = lane >> 4;                      // 0..3
  const int lk = hi * 8;
  const int row0 = blockIdx.x * 32;

  // ---- stage: 16 threads/row ----
  {
    const int row = tid >> 4;                    // 0..31
    const int sub = tid & 15;
    const int grow = row0 + row;
    const int swz = row & 7;
    uint4* lds = (uint4*)xs + row * G;
    // independent loads first (latency overlaps the gather chain)
    uint4 vh = {0, 0, 0, 0}, vx = {0, 0, 0, 0};
    if (grow < N) {
      vh = *reinterpret_cast<const uint4*>(Hin + (size_t)grow * HDIM + sub * 8);
      if (HAS_X1) {
        int sr = (grow < Vhalf) ? grow + Vhalf : grow - Vhalf;
        vx = *reinterpret_cast<const uint4*>(X1 + (size_t)sr * HDIM + sub * 8);
      }
    }
    // dependent CSR gather
    float a[8];
#pragma unroll
    for (int t = 0; t < 8; ++t) a[t] = 0.f;
    if (grow < N) {
      int s0 = moff[grow], s1 = moff[grow + 1];
      for (int j = s0; j < s1; ++j) {
        uint4 r = *reinterpret_cast<const uint4*>(
            msgs + (size_t)mvals[j] * HDIM + sub * 8);
        float f[8]; unpack8(r, f);
#pragma unroll
        for (int t = 0; t < 8; ++t) a[t] += f[t];
      }
    }
    uint4 pk;
    pk.x = (u32)f2bf(a[0]) | ((u32)f2bf(a[1]) << 16);
    pk.y = (u32)f2bf(a[2]) | ((u32)f2bf(a[3]) << 16);
    pk.z = (u32)f2bf(a[4]) | ((u32)f2bf(a[5]) << 16);
    pk.w = (u32)f2bf(a[6]) | ((u32)f2bf(a[7]) << 16);
    lds[sub ^ swz] = pk;
    if (HAS_X1) lds[(16 + sub) ^ swz] = vx;
    lds[((HAS_X1 ? 32 : 16) + sub) ^ swz] = vh;
  }
  __syncthreads();

  f32x4 zc = {0.f, 0.f, 0.f, 0.f};
  f32x4 acc[2][4];
#pragma unroll
  for (int rt = 0; rt < 2; ++rt)
#pragma unroll
    for (int q = 0; q < 4; ++q) acc[rt][q] = zc;

  for (int ks = 0; ks < KS; ++ks) {
    bf16x8 bfr[4];
#pragma unroll
    for (int q = 0; q < 4; ++q) {
      int col = q * 128 + w * 16 + lr;
      bfr[q] = *reinterpret_cast<const bf16x8*>(WT + (size_t)col * KT + ks * 32 + lk);
    }
#pragma unroll
    for (int rt = 0; rt < 2; ++rt) {
      int row = rt * 16 + lr;
      bf16x8 a = ((const bf16x8*)xs)[row * G + ((ks * 4 + hi) ^ (row & 7))];
#pragma unroll
      for (int q = 0; q < 4; ++q)
        acc[rt][q] = __builtin_amdgcn_mfma_f32_16x16x32_bf16(a, bfr[q], acc[rt][q], 0, 0, 0);
    }
  }

  // ---- epilogue (wave-local) ----
  const int m = w * 16 + lr;
  float bv[4];
#pragma unroll
  for (int q = 0; q < 4; ++q) bv[q] = Bias[q * 128 + m];

  if (row0 + 32 <= N) {
#pragma unroll
    for (int rt = 0; rt < 2; ++rt) {
      size_t cb = ((size_t)((row0 >> 4) + rt) * 128 + m) * 16 + hi * 4;
      float4 cin = *reinterpret_cast<const float4*>(Cin + cb);
      float4 cout;
      float hn[4];
#pragma unroll
      for (int reg = 0; reg < 4; ++reg) {
        float gi = acc[rt][0][reg] + bv[0];
        float gf = acc[rt][1][reg] + bv[1];
        float gg = acc[rt][2][reg] + bv[2];
        float go = acc[rt][3][reg] + bv[3];
        float co = (&cin.x)[reg];
        float cn = sigm_f(gf) * co + sigm_f(gi) * tanh_f(gg);
        hn[reg] = sigm_f(go) * tanh_f(cn);
        (&cout.x)[reg] = cn;
      }
      *reinterpret_cast<float4*>(Cout + cb) = cout;
      int rowb = row0 + rt * 16 + hi * 4;
#pragma unroll
      for (int reg = 0; reg < 4; ++reg) {
        size_t hidx = (size_t)(rowb + reg) * HDIM + m;
        if (OUT_F32) ((float*)Hout)[hidx] = hn[reg];
        else         ((u16*)Hout)[hidx]   = f2bf(hn[reg]);
      }
    }
  } else {
#pragma unroll
    for (int rt = 0; rt < 2; ++rt)
#pragma unroll
      for (int reg = 0; reg < 4; ++reg) {
        int row = row0 + rt * 16 + hi * 4 + reg;
        if (row >= N) continue;
        size_t cb = ((size_t)(row >> 4) * 128 + m) * 16 + (row & 15);
        float gi = acc[rt][0][reg] + bv[0];
        float gf = acc[rt][1][reg] + bv[1];
        float gg = acc[rt][2][reg] + bv[2];
        float go = acc[rt][3][reg] + bv[3];
        float co = Cin[cb];
        float cn = sigm_f(gf) * co + sigm_f(gi) * tanh_f(gg);
        float hn = sigm_f(go) * tanh_f(cn);
        Cout[cb] = cn;
        size_t hidx = (size_t)row * HDIM + m;
        if (OUT_F32) ((float*)Hout)[hidx] = hn;
        else         ((u16*)Hout)[hidx]   = f2bf(hn);
      }
  }
}

// ---------- launch ----------
extern "C" void kernel_launch(void* const* d_in, const int* in_sizes, int n_in,
                              void* d_out, int out_size, void* d_ws, size_t ws_size,
                              hipStream_t stream) {
  const int V = in_sizes[0] / (2 * HDIM);
  const int L = 2 * V;
  const int C = in_sizes[1] / HDIM;
  const int E = in_sizes[2];
  const int R = 4;

  const void* l_emb = d_in[0];
  const void* c_emb = d_in[1];
  const int* eps  = (const int*)d_in[2];
  const int* epd  = (const int*)d_in[3];
  const int* ens  = (const int*)d_in[4];
  const int* end_ = (const int*)d_in[5];

  const size_t LH = (size_t)L * HDIM;
  const size_t CH = (size_t)C * HDIM;

  char* base = (char*)d_ws;
  auto alloc = [&](size_t bytes) -> char* {
    char* r = base; base += (bytes + 255) / 256 * 256; return r;
  };
  u16* l_hA  = (u16*)alloc(LH * 2);
  u16* l_hB  = (u16*)alloc(LH * 2);
  u16* c_h   = (u16*)alloc(CH * 2);
  u16* tL    = (u16*)alloc(LH * 2);
  u16* tC    = (u16*)alloc(CH * 2);
  float* l_c = (float*)alloc(LH * 4);
  float* c_c = (float*)alloc(CH * 4);
  u16* WT_lmlp[3]; u16* WT_cmlp[3];
  for (int j = 0; j < 3; ++j) WT_lmlp[j] = (u16*)alloc(HDIM * HDIM * 2);
  for (int j = 0; j < 3; ++j) WT_cmlp[j] = (u16*)alloc(HDIM * HDIM * 2);
  u16* WT_l = (u16*)alloc(512 * 384 * 2);
  u16* WT_c = (u16*)alloc(512 * 256 * 2);
  float* Bf_lmlp[3]; float* Bf_cmlp[3];
  for (int j = 0; j < 3; ++j) Bf_lmlp[j] = (float*)alloc(HDIM * 4);
  for (int j = 0; j < 3; ++j) Bf_cmlp[j] = (float*)alloc(HDIM * 4);
  float* Bf_l = (float*)alloc(512 * 4);
  float* Bf_c = (float*)alloc(512 * 4);
  int* deg1 = (int*)alloc((size_t)C * 4);
  int* off1 = (int*)alloc(((size_t)C + 1) * 4);
  int* cur1 = (int*)alloc((size_t)C * 4);
  int* vals1 = (int*)alloc((size_t)2 * E * 4);
  int* deg2 = (int*)alloc((size_t)L * 4);
  int* off2 = (int*)alloc(((size_t)L + 1) * 4);
  int* cur2 = (int*)alloc((size_t)L * 4);
  int* vals2 = (int*)alloc((size_t)2 * E * 4);
  int* inc  = (int*)alloc((size_t)(C > L ? C : L) * 4);
  int* bsum = (int*)alloc(256 * 4);
  int* flag = (int*)alloc(256);

  size_t required = (size_t)(base - (char*)d_ws);
  if (required > ws_size) {
    float val = 64.0f + (float)(ws_size >> 26);
    k_sentinel<<<(out_size + 255) / 256, 256, 0, stream>>>((float*)d_out, out_size, val);
    return;
  }

  // ---- dtype detect + weight prep ----
  k_detect<<<1, 256, 0, stream>>>((const u32*)d_in[6], flag);
  const int mlp_tot = HDIM * HDIM;
  for (int j = 0; j < 3; ++j) {
    k_build_wt<<<(mlp_tot + 255) / 256, 256, 0, stream>>>(
        d_in[6 + 2 * j], d_in[6 + 2 * j], HDIM, HDIM, HDIM, WT_lmlp[j], flag);
    k_build_wt<<<(mlp_tot + 255) / 256, 256, 0, stream>>>(
        d_in[12 + 2 * j], d_in[12 + 2 * j], HDIM, HDIM, HDIM, WT_cmlp[j], flag);
  }
  k_build_wt<<<(512 * 384 + 255) / 256, 256, 0, stream>>>(
      d_in[18], d_in[19], 256, 384, 512, WT_l, flag);
  k_build_wt<<<(512 * 256 + 255) / 256, 256, 0, stream>>>(
      d_in[21], d_in[22], 128, 256, 512, WT_c, flag);
  k_any_to_f32<<<1, 256, 0, stream>>>(d_in[7],  Bf_lmlp[0], HDIM / 8, flag);
  k_any_to_f32<<<1, 256, 0, stream>>>(d_in[9],  Bf_lmlp[1], HDIM / 8, flag);
  k_any_to_f32<<<1, 256, 0, stream>>>(d_in[11], Bf_lmlp[2], HDIM / 8, flag);
  k_any_to_f32<<<1, 256, 0, stream>>>(d_in[13], Bf_cmlp[0], HDIM / 8, flag);
  k_any_to_f32<<<1, 256, 0, stream>>>(d_in[15], Bf_cmlp[1], HDIM / 8, flag);
  k_any_to_f32<<<1, 256, 0, stream>>>(d_in[17], Bf_cmlp[2], HDIM / 8, flag);
  k_any_to_f32<<<1, 256, 0, stream>>>(d_in[20], Bf_l, 512 / 8, flag);
  k_any_to_f32<<<1, 256, 0, stream>>>(d_in[23], Bf_c, 512 / 8, flag);

  // ---- CSR build ----
  const int gE = (E + 255) / 256;
  (void)hipMemsetAsync(deg1, 0, (size_t)C * 4, stream);
  (void)hipMemsetAsync(deg2, 0, (size_t)L * 4, stream);
  k_count<<<gE, 256, 0, stream>>>(epd, 0, E, deg1);
  k_count<<<gE, 256, 0, stream>>>(end_, 0, E, deg1);
  k_count<<<gE, 256, 0, stream>>>(eps, 0, E, deg2);
  k_count<<<gE, 256, 0, stream>>>(ens, V, E, deg2);
  {
    int nb = (C + 1023) / 1024;
    k_scan1<<<nb, 256, 0, stream>>>(deg1, inc, bsum, C);
    k_scan2<<<1, 256, 0, stream>>>(bsum, nb);
    k_scan3<<<(C + 255) / 256, 256, 0, stream>>>(inc, bsum, off1, cur1, C);
  }
  {
    int nb = (L + 1023) / 1024;
    k_scan1<<<nb, 256, 0, stream>>>(deg2, inc, bsum, L);
    k_scan2<<<1, 256, 0, stream>>>(bsum, nb);
    k_scan3<<<(L + 255) / 256, 256, 0, stream>>>(inc, bsum, off2, cur2, L);
  }
  k_fill<<<gE, 256, 0, stream>>>(epd, 0, eps, 0, E, cur1, vals1);
  k_fill<<<gE, 256, 0, stream>>>(end_, 0, ens, V, E, cur1, vals1);
  k_fill<<<gE, 256, 0, stream>>>(eps, 0, epd, 0, E, cur2, vals2);
  k_fill<<<gE, 256, 0, stream>>>(ens, V, end_, 0, E, cur2, vals2);

  // ---- init states ----
  k_any_to_bf16<<<(int)((LH / 8 + 255) / 256), 256, 0, stream>>>(l_emb, l_hA, (int)(LH / 8), flag);
  k_any_to_bf16<<<(int)((CH / 8 + 255) / 256), 256, 0, stream>>>(c_emb, c_h, (int)(CH / 8), flag);
  (void)hipMemsetAsync(l_c, 0, LH * sizeof(float), stream);
  (void)hipMemsetAsync(c_c, 0, CH * sizeof(float), stream);

  u16* lh_cur = l_hA;
  u16* lh_nxt = l_hB;
  float* outf = (float*)d_out;

  const int gm_l = (L + 127) / 128;
  const int gm_c = (C + 127) / 128;
  const int gs_c = (C + 31) / 32;
  const int gs_l = (L + 31) / 32;

  for (int r = 0; r < R; ++r) {
    // literal MLP3 -> tL, clause MLP3 -> tC
    k_mlp3<<<gm_l, 256, 0, stream>>>(lh_cur, tL, L,
        WT_lmlp[0], Bf_lmlp[0], WT_lmlp[1], Bf_lmlp[1], WT_lmlp[2], Bf_lmlp[2]);
    k_mlp3<<<gm_c, 256, 0, stream>>>(c_h, tC, C,
        WT_cmlp[0], Bf_cmlp[0], WT_cmlp[1], Bf_cmlp[1], WT_cmlp[2], Bf_cmlp[2]);
    // LSTMs with fused gather (final round writes f32 h straight to d_out)
    if (r == R - 1) {
      k_lstm4<0, 1><<<gs_c, 512, 0, stream>>>(
          tL, off1, vals1, (const u16*)nullptr, 0, c_h, c_c,
          (void*)(outf + LH), c_c, WT_c, Bf_c, C);
      k_lstm4<1, 1><<<gs_l, 512, 0, stream>>>(
          tC, off2, vals2, lh_cur, V, lh_cur, l_c,
          (void*)outf, l_c, WT_l, Bf_l, L);
    } else {
      k_lstm4<0, 0><<<gs_c, 512, 0, stream>>>(
          tL, off1, vals1, (const u16*)nullptr, 0, c_h, c_c,
          (void*)c_h, c_c, WT_c, Bf_c, C);
      k_lstm4<1, 0><<<gs_l, 512, 0, stream>>>(
          tC, off2, vals2, lh_cur, V, lh_cur, l_c,
          (void*)lh_nxt, l_c, WT_l, Bf_l, L);
      u16* tmp = lh_cur; lh_cur = lh_nxt; lh_nxt = tmp;
    }
  }
}

// Round 10
// 1876.096 us; speedup vs baseline: 1.6872x; 1.6872x over previous
//
#include <hip/hip_runtime.h>
#include <hip/hip_bf16.h>

#define HDIM 128

using u16 = unsigned short;
using u32 = unsigned int;
using bf16x8 = __attribute__((ext_vector_type(8))) short;
using f32x4  = __attribute__((ext_vector_type(4))) float;

// ---------- helpers ----------
__device__ __forceinline__ float bf2f(u32 b) {
  union { u32 i; float f; } x; x.i = b << 16; return x.f;
}
__device__ __forceinline__ u16 f2bf(float f) {
  union { float f; u32 i; } x; x.f = f; u32 u = x.i;
  return (u16)((u + 0x7fffu + ((u >> 16) & 1u)) >> 16);
}
__device__ __forceinline__ void unpack8(uint4 r, float* o) {
  o[0] = bf2f(r.x & 0xffffu); o[1] = bf2f(r.x >> 16);
  o[2] = bf2f(r.y & 0xffffu); o[3] = bf2f(r.y >> 16);
  o[4] = bf2f(r.z & 0xffffu); o[5] = bf2f(r.z >> 16);
  o[6] = bf2f(r.w & 0xffffu); o[7] = bf2f(r.w >> 16);
}
__device__ __forceinline__ float sigm_f(float x) {
  return __builtin_amdgcn_rcpf(1.f + __expf(-x));
}
__device__ __forceinline__ float tanh_f(float x) {
  return 2.f * __builtin_amdgcn_rcpf(1.f + __expf(-2.f * x)) - 1.f;
}

// ---------- dtype detector (flag=1 -> inputs are packed bf16) ----------
__global__ __launch_bounds__(256) void k_detect(const u32* __restrict__ probe,
                                                int* __restrict__ flag) {
  __shared__ int cnt;
  if (threadIdx.x == 0) cnt = 0;
  __syncthreads();
  int local = 0;
  for (int i = threadIdx.x; i < 1024; i += 256) {
    u32 e = (probe[i] >> 7) & 0xFF;
    if (e >= 96 && e <= 126) local++;
  }
  atomicAdd(&cnt, local);
  __syncthreads();
  if (threadIdx.x == 0) *flag = (cnt > 512) ? 1 : 0;
}

// ---------- converters ----------
__global__ __launch_bounds__(256) void k_any_to_f32(
    const void* __restrict__ src, float* __restrict__ dst, int n8,
    const int* __restrict__ flag) {
  int i = blockIdx.x * 256 + threadIdx.x;
  if (i >= n8) return;
  float t[8];
  if (*flag) {
    uint4 raw = ((const uint4*)src)[i];
    unpack8(raw, t);
  } else {
    const float4* s = ((const float4*)src) + 2 * (size_t)i;
    float4 a = s[0], b = s[1];
    t[0] = a.x; t[1] = a.y; t[2] = a.z; t[3] = a.w;
    t[4] = b.x; t[5] = b.y; t[6] = b.z; t[7] = b.w;
  }
  float4* o = ((float4*)dst) + 2 * (size_t)i;
  o[0] = make_float4(t[0], t[1], t[2], t[3]);
  o[1] = make_float4(t[4], t[5], t[6], t[7]);
}

__global__ __launch_bounds__(256) void k_any_to_bf16(
    const void* __restrict__ src, u16* __restrict__ dst, int n8,
    const int* __restrict__ flag) {
  int i = blockIdx.x * 256 + threadIdx.x;
  if (i >= n8) return;
  uint4 o;
  if (*flag) {
    o = ((const uint4*)src)[i];
  } else {
    const float4* s = ((const float4*)src) + 2 * (size_t)i;
    float4 a = s[0], b = s[1];
    o.x = (u32)f2bf(a.x) | ((u32)f2bf(a.y) << 16);
    o.y = (u32)f2bf(a.z) | ((u32)f2bf(a.w) << 16);
    o.z = (u32)f2bf(b.x) | ((u32)f2bf(b.y) << 16);
    o.w = (u32)f2bf(b.z) | ((u32)f2bf(b.w) << 16);
  }
  ((uint4*)dst)[i] = o;
}

// ---------- build transposed bf16 weights: WT[n][k], k<KX from Wih, else Whh ----------
__global__ __launch_bounds__(256) void k_build_wt(
    const void* __restrict__ Wih, const void* __restrict__ Whh, int KX, int Ktot,
    int Ncols, u16* __restrict__ WT, const int* __restrict__ flag) {
  int idx = blockIdx.x * 256 + threadIdx.x;
  int total = Ncols * Ktot;
  if (idx >= total) return;
  int n = idx / Ktot, k = idx - n * Ktot;
  const void* src = (k < KX) ? Wih : Whh;
  int kk = (k < KX) ? k : k - KX;
  size_t off = (size_t)kk * Ncols + n;
  u16 b;
  if (*flag) b = ((const u16*)src)[off];
  else       b = f2bf(((const float*)src)[off]);
  WT[(size_t)n * Ktot + k] = b;
}

// ---------- diagnostic sentinel (ws too small) ----------
__global__ __launch_bounds__(256) void k_sentinel(float* __restrict__ out,
                                                  int n, float val) {
  int i = blockIdx.x * 256 + threadIdx.x;
  if (i < n) out[i] = val;
}

// ---------- CSR build: count / scan / fill ----------
__global__ __launch_bounds__(256) void k_count(
    const int* __restrict__ key, int key_add, int E, int* __restrict__ deg) {
  int e = blockIdx.x * 256 + threadIdx.x;
  if (e < E) atomicAdd(&deg[key[e] + key_add], 1);
}

__global__ __launch_bounds__(256) void k_scan1(
    const int* __restrict__ in, int* __restrict__ inc,
    int* __restrict__ bsum, int n) {
  __shared__ int s[256];
  const int tid = threadIdx.x;
  const int b0 = blockIdx.x * 1024;
  int v[4]; int sum = 0;
#pragma unroll
  for (int j = 0; j < 4; ++j) {
    int i = b0 + tid * 4 + j;
    int x = (i < n) ? in[i] : 0;
    sum += x; v[j] = sum;
  }
  s[tid] = sum;
  __syncthreads();
  for (int d = 1; d < 256; d <<= 1) {
    int t = (tid >= d) ? s[tid - d] : 0;
    __syncthreads();
    s[tid] += t;
    __syncthreads();
  }
  int base = (tid > 0) ? s[tid - 1] : 0;
#pragma unroll
  for (int j = 0; j < 4; ++j) {
    int i = b0 + tid * 4 + j;
    if (i < n) inc[i] = base + v[j];
  }
  if (tid == 255) bsum[blockIdx.x] = s[255];
}

__global__ __launch_bounds__(256) void k_scan2(int* __restrict__ bsum, int nb) {
  __shared__ int s[256];
  const int tid = threadIdx.x;
  int x = (tid < nb) ? bsum[tid] : 0;
  s[tid] = x;
  __syncthreads();
  for (int d = 1; d < 256; d <<= 1) {
    int t = (tid >= d) ? s[tid - d] : 0;
    __syncthreads();
    s[tid] += t;
    __syncthreads();
  }
  if (tid < nb) bsum[tid] = (tid > 0) ? s[tid - 1] : 0;
}

__global__ __launch_bounds__(256) void k_scan3(
    const int* __restrict__ inc, const int* __restrict__ bsum,
    int* __restrict__ off, int* __restrict__ cursor, int n) {
  int i = blockIdx.x * 256 + threadIdx.x;
  if (i < n) {
    int v = inc[i] + bsum[i >> 10];
    off[i + 1] = v;
    int prev = (i & 1023) ? (inc[i - 1] + bsum[i >> 10]) : bsum[i >> 10];
    cursor[i] = prev;
    if (i == 0) { off[0] = 0; cursor[0] = 0; }
  }
}

__global__ __launch_bounds__(256) void k_fill(
    const int* __restrict__ key, int key_add,
    const int* __restrict__ pay, int pay_add, int E,
    int* __restrict__ cursor, int* __restrict__ vals) {
  int e = blockIdx.x * 256 + threadIdx.x;
  if (e >= E) return;
  int k = key[e] + key_add;
  int p = atomicAdd(&cursor[k], 1);
  vals[p] = pay[e] + pay_add;
}

// ---------- fused 3-layer MLP: Y = (relu(relu(X@W0+b0)@W1+b1))@W2+b2 ----------
// 128 rows/block, 256 thr (4 waves). Layers chained through XOR-swizzled LDS.
__global__ __launch_bounds__(256) void k_mlp3(
    const u16* __restrict__ X, u16* __restrict__ Y, int N,
    const u16* __restrict__ WT0, const float* __restrict__ B0,
    const u16* __restrict__ WT1, const float* __restrict__ B1,
    const u16* __restrict__ WT2, const float* __restrict__ B2) {
  __shared__ u16 xs[128 * 128];  // 32 KB
  const int tid = threadIdx.x;
  const int lane = tid & 63;
  const int w = tid >> 6;        // 0..3
  const int lr = lane & 15;
  const int hi = lane >> 4;      // 0..3
  const int lk = hi * 8;
  const int row0 = blockIdx.x * 128;

  {
    const int row = tid >> 1, half = tid & 1;
    const int grow = row0 + row;
#pragma unroll
    for (int j = 0; j < 8; ++j) {
      int g = half * 8 + j;
      uint4 v = {0, 0, 0, 0};
      if (grow < N) v = *reinterpret_cast<const uint4*>(X + (size_t)grow * HDIM + g * 8);
      ((uint4*)xs)[row * 16 + (g ^ (row & 7))] = v;
    }
  }
  __syncthreads();

  const u16* WTs[3] = {WT0, WT1, WT2};
  const float* Bs[3] = {B0, B1, B2};
#pragma unroll
  for (int layer = 0; layer < 3; ++layer) {
    f32x4 zc = {0.f, 0.f, 0.f, 0.f};
    f32x4 acc[8][2];
#pragma unroll
    for (int rt = 0; rt < 8; ++rt) { acc[rt][0] = zc; acc[rt][1] = zc; }
#pragma unroll
    for (int ks = 0; ks < 4; ++ks) {
      bf16x8 bfr[2];
#pragma unroll
      for (int t = 0; t < 2; ++t) {
        int col = w * 32 + t * 16 + lr;
        bfr[t] = *reinterpret_cast<const bf16x8*>(
            WTs[layer] + (size_t)col * HDIM + ks * 32 + lk);
      }
#pragma unroll
      for (int rt = 0; rt < 8; ++rt) {
        int row = rt * 16 + lr;
        int g = ks * 4 + hi;
        bf16x8 a = ((const bf16x8*)xs)[row * 16 + (g ^ (row & 7))];
        acc[rt][0] = __builtin_amdgcn_mfma_f32_16x16x32_bf16(a, bfr[0], acc[rt][0], 0, 0, 0);
        acc[rt][1] = __builtin_amdgcn_mfma_f32_16x16x32_bf16(a, bfr[1], acc[rt][1], 0, 0, 0);
      }
    }
    float bv[2];
    bv[0] = Bs[layer][w * 32 + lr];
    bv[1] = Bs[layer][w * 32 + 16 + lr];
    __syncthreads();
    if (layer < 2) {
#pragma unroll
      for (int rt = 0; rt < 8; ++rt)
#pragma unroll
        for (int t = 0; t < 2; ++t) {
          int col = w * 32 + t * 16 + lr;
          int g = col >> 3, cw = col & 7;
#pragma unroll
          for (int reg = 0; reg < 4; ++reg) {
            int row = rt * 16 + hi * 4 + reg;
            float v = fmaxf(acc[rt][t][reg] + bv[t], 0.f);
            xs[(row * 16 + (g ^ (row & 7))) * 8 + cw] = f2bf(v);
          }
        }
      __syncthreads();
    } else {
#pragma unroll
      for (int rt = 0; rt < 8; ++rt)
#pragma unroll
        for (int t = 0; t < 2; ++t) {
          int col = w * 32 + t * 16 + lr;
#pragma unroll
          for (int reg = 0; reg < 4; ++reg) {
            int row = row0 + rt * 16 + hi * 4 + reg;
            if (row < N) Y[(size_t)row * HDIM + col] = f2bf(acc[rt][t][reg] + bv[t]);
          }
        }
    }
  }
}

// ---------- MFMA LSTM with fused CSR gather, 64 rows/block, 512 thr (r7 champion) ----------
// FIRST: c_in == 0 (skip Cin load). LAST: cell-state output dead (skip Cout store).
template<int HAS_X1, int OUT_F32, int FIRST, int LAST>
__global__ __launch_bounds__(512) void k_lstm3(
    const u16* __restrict__ msgs, const int* __restrict__ moff,
    const int* __restrict__ mvals,
    const u16* __restrict__ X1, int Vhalf,
    const u16* __restrict__ Hin, const float* __restrict__ Cin,
    void* __restrict__ Hout, float* __restrict__ Cout,
    const u16* __restrict__ WT, const float* __restrict__ Bias, int N) {
  const int KT = HAS_X1 ? 384 : 256;
  const int KS = KT / 32;
  const int G = KT / 8;                 // 16B granules per row
  __shared__ u16 xs[64 * (HAS_X1 ? 384 : 256)];  // 48 or 32 KB
  const int tid = threadIdx.x;
  const int lane = tid & 63;
  const int w = tid >> 6;               // 0..7
  const int lr = lane & 15;
  const int hi = lane >> 4;             // 0..3
  const int lk = hi * 8;
  const int row0 = blockIdx.x * 64;

  // ---- stage: 8 threads/row ----
  {
    const int row = tid >> 3, sub = tid & 7;
    const int grow = row0 + row;
    const int swz = row & 7;
    uint4* lds = (uint4*)xs + row * G;
    // hoist CSR range first so the gather's first data load issues early
    int s0 = 0, s1 = 0;
    if (grow < N) { s0 = moff[grow]; s1 = moff[grow + 1]; }
    // independent loads (overlap with gather chain)
    uint4 vh = {0, 0, 0, 0}, vx = {0, 0, 0, 0};
    if (grow < N) {
      vh = *reinterpret_cast<const uint4*>(Hin + (size_t)grow * HDIM + sub * 16);
      // second half of Hin granule pair handled below via two stores; load both
    }
    uint4 vh1 = {0, 0, 0, 0}, vx1 = {0, 0, 0, 0};
    if (grow < N) {
      vh1 = *reinterpret_cast<const uint4*>(Hin + (size_t)grow * HDIM + sub * 16 + 8);
      if (HAS_X1) {
        int sr = (grow < Vhalf) ? grow + Vhalf : grow - Vhalf;
        vx  = *reinterpret_cast<const uint4*>(X1 + (size_t)sr * HDIM + sub * 16);
        vx1 = *reinterpret_cast<const uint4*>(X1 + (size_t)sr * HDIM + sub * 16 + 8);
      }
    }
    // dependent CSR gather, unrolled x2 (two 256B rows in flight)
    float a[16];
#pragma unroll
    for (int t = 0; t < 16; ++t) a[t] = 0.f;
    {
      int j = s0;
      for (; j + 1 < s1; j += 2) {
        int v0 = mvals[j], v1 = mvals[j + 1];
        const uint4* p0 = reinterpret_cast<const uint4*>(msgs + (size_t)v0 * HDIM + sub * 16);
        const uint4* p1 = reinterpret_cast<const uint4*>(msgs + (size_t)v1 * HDIM + sub * 16);
        uint4 r0 = p0[0], r1 = p0[1], r2 = p1[0], r3 = p1[1];
        float f0[8], f1[8], f2[8], f3[8];
        unpack8(r0, f0); unpack8(r1, f1); unpack8(r2, f2); unpack8(r3, f3);
#pragma unroll
        for (int t = 0; t < 8; ++t) {
          a[t]     += f0[t] + f2[t];
          a[8 + t] += f1[t] + f3[t];
        }
      }
      if (j < s1) {
        const uint4* p = reinterpret_cast<const uint4*>(msgs + (size_t)mvals[j] * HDIM + sub * 16);
        uint4 r0 = p[0], r1 = p[1];
        float f0[8], f1[8];
        unpack8(r0, f0); unpack8(r1, f1);
#pragma unroll
        for (int t = 0; t < 8; ++t) { a[t] += f0[t]; a[8 + t] += f1[t]; }
      }
    }
    uint4 pk;
    pk.x = (u32)f2bf(a[0]) | ((u32)f2bf(a[1]) << 16);
    pk.y = (u32)f2bf(a[2]) | ((u32)f2bf(a[3]) << 16);
    pk.z = (u32)f2bf(a[4]) | ((u32)f2bf(a[5]) << 16);
    pk.w = (u32)f2bf(a[6]) | ((u32)f2bf(a[7]) << 16);
    lds[(sub * 2) ^ swz] = pk;
    pk.x = (u32)f2bf(a[8])  | ((u32)f2bf(a[9])  << 16);
    pk.y = (u32)f2bf(a[10]) | ((u32)f2bf(a[11]) << 16);
    pk.z = (u32)f2bf(a[12]) | ((u32)f2bf(a[13]) << 16);
    pk.w = (u32)f2bf(a[14]) | ((u32)f2bf(a[15]) << 16);
    lds[(sub * 2 + 1) ^ swz] = pk;
    if (HAS_X1) {
      lds[(16 + sub * 2) ^ swz] = vx;
      lds[(16 + sub * 2 + 1) ^ swz] = vx1;
    }
    {
      int gb = (HAS_X1 ? 32 : 16) + sub * 2;
      lds[gb ^ swz] = vh;
      lds[(gb + 1) ^ swz] = vh1;
    }
  }
  __syncthreads();

  f32x4 zc = {0.f, 0.f, 0.f, 0.f};
  f32x4 acc[4][4];
#pragma unroll
  for (int rt = 0; rt < 4; ++rt)
#pragma unroll
    for (int q = 0; q < 4; ++q) acc[rt][q] = zc;

#pragma unroll
  for (int ks = 0; ks < KS; ++ks) {
    bf16x8 bfr[4];
#pragma unroll
    for (int q = 0; q < 4; ++q) {
      int col = q * 128 + w * 16 + lr;
      bfr[q] = *reinterpret_cast<const bf16x8*>(WT + (size_t)col * KT + ks * 32 + lk);
    }
#pragma unroll
    for (int rt = 0; rt < 4; ++rt) {
      int row = rt * 16 + lr;
      bf16x8 a = ((const bf16x8*)xs)[row * G + ((ks * 4 + hi) ^ (row & 7))];
#pragma unroll
      for (int q = 0; q < 4; ++q)
        acc[rt][q] = __builtin_amdgcn_mfma_f32_16x16x32_bf16(a, bfr[q], acc[rt][q], 0, 0, 0);
    }
  }

  // ---- epilogue (wave-local) ----
  const int m = w * 16 + lr;
  float bv[4];
#pragma unroll
  for (int q = 0; q < 4; ++q) bv[q] = Bias[q * 128 + m];

  if (row0 + 64 <= N) {
#pragma unroll
    for (int rt = 0; rt < 4; ++rt) {
      size_t cb = ((size_t)((row0 >> 4) + rt) * 128 + m) * 16 + hi * 4;
      float4 cin = make_float4(0.f, 0.f, 0.f, 0.f);
      if (!FIRST) cin = *reinterpret_cast<const float4*>(Cin + cb);
      float4 cout;
      float hn[4];
#pragma unroll
      for (int reg = 0; reg < 4; ++reg) {
        float gi = acc[rt][0][reg] + bv[0];
        float gf = acc[rt][1][reg] + bv[1];
        float gg = acc[rt][2][reg] + bv[2];
        float go = acc[rt][3][reg] + bv[3];
        float co = (&cin.x)[reg];
        float cn = sigm_f(gf) * co + sigm_f(gi) * tanh_f(gg);
        hn[reg] = sigm_f(go) * tanh_f(cn);
        (&cout.x)[reg] = cn;
      }
      if (!LAST) *reinterpret_cast<float4*>(Cout + cb) = cout;
      int rowb = row0 + rt * 16 + hi * 4;
#pragma unroll
      for (int reg = 0; reg < 4; ++reg) {
        size_t hidx = (size_t)(rowb + reg) * HDIM + m;
        if (OUT_F32) ((float*)Hout)[hidx] = hn[reg];
        else         ((u16*)Hout)[hidx]   = f2bf(hn[reg]);
      }
    }
  } else {
#pragma unroll
    for (int rt = 0; rt < 4; ++rt)
#pragma unroll
      for (int reg = 0; reg < 4; ++reg) {
        int row = row0 + rt * 16 + hi * 4 + reg;
        if (row >= N) continue;
        size_t cb = ((size_t)(row >> 4) * 128 + m) * 16 + (row & 15);
        float gi = acc[rt][0][reg] + bv[0];
        float gf = acc[rt][1][reg] + bv[1];
        float gg = acc[rt][2][reg] + bv[2];
        float go = acc[rt][3][reg] + bv[3];
        float co = FIRST ? 0.f : Cin[cb];
        float cn = sigm_f(gf) * co + sigm_f(gi) * tanh_f(gg);
        float hn = sigm_f(go) * tanh_f(cn);
        if (!LAST) Cout[cb] = cn;
        size_t hidx = (size_t)row * HDIM + m;
        if (OUT_F32) ((float*)Hout)[hidx] = hn;
        else         ((u16*)Hout)[hidx]   = f2bf(hn);
      }
  }
}

// ---------- launch ----------
extern "C" void kernel_launch(void* const* d_in, const int* in_sizes, int n_in,
                              void* d_out, int out_size, void* d_ws, size_t ws_size,
                              hipStream_t stream) {
  const int V = in_sizes[0] / (2 * HDIM);
  const int L = 2 * V;
  const int C = in_sizes[1] / HDIM;
  const int E = in_sizes[2];
  const int R = 4;

  const void* l_emb = d_in[0];
  const void* c_emb = d_in[1];
  const int* eps  = (const int*)d_in[2];
  const int* epd  = (const int*)d_in[3];
  const int* ens  = (const int*)d_in[4];
  const int* end_ = (const int*)d_in[5];

  const size_t LH = (size_t)L * HDIM;
  const size_t CH = (size_t)C * HDIM;

  char* base = (char*)d_ws;
  auto alloc = [&](size_t bytes) -> char* {
    char* r = base; base += (bytes + 255) / 256 * 256; return r;
  };
  u16* l_hA  = (u16*)alloc(LH * 2);
  u16* l_hB  = (u16*)alloc(LH * 2);
  u16* c_h   = (u16*)alloc(CH * 2);
  u16* tL    = (u16*)alloc(LH * 2);   // literal messages
  u16* tC    = (u16*)alloc(CH * 2);   // clause messages
  float* l_c = (float*)alloc(LH * 4); // tiled layout
  float* c_c = (float*)alloc(CH * 4);
  u16* WT_lmlp[3]; u16* WT_cmlp[3];
  for (int j = 0; j < 3; ++j) WT_lmlp[j] = (u16*)alloc(HDIM * HDIM * 2);
  for (int j = 0; j < 3; ++j) WT_cmlp[j] = (u16*)alloc(HDIM * HDIM * 2);
  u16* WT_l = (u16*)alloc(512 * 384 * 2);
  u16* WT_c = (u16*)alloc(512 * 256 * 2);
  float* Bf_lmlp[3]; float* Bf_cmlp[3];
  for (int j = 0; j < 3; ++j) Bf_lmlp[j] = (float*)alloc(HDIM * 4);
  for (int j = 0; j < 3; ++j) Bf_cmlp[j] = (float*)alloc(HDIM * 4);
  float* Bf_l = (float*)alloc(512 * 4);
  float* Bf_c = (float*)alloc(512 * 4);
  int* deg1 = (int*)alloc((size_t)C * 4);
  int* off1 = (int*)alloc(((size_t)C + 1) * 4);
  int* cur1 = (int*)alloc((size_t)C * 4);
  int* vals1 = (int*)alloc((size_t)2 * E * 4);
  int* deg2 = (int*)alloc((size_t)L * 4);
  int* off2 = (int*)alloc(((size_t)L + 1) * 4);
  int* cur2 = (int*)alloc((size_t)L * 4);
  int* vals2 = (int*)alloc((size_t)2 * E * 4);
  int* inc  = (int*)alloc((size_t)(C > L ? C : L) * 4);
  int* bsum = (int*)alloc(256 * 4);
  int* flag = (int*)alloc(256);

  size_t required = (size_t)(base - (char*)d_ws);
  if (required > ws_size) {
    float val = 64.0f + (float)(ws_size >> 26);
    k_sentinel<<<(out_size + 255) / 256, 256, 0, stream>>>((float*)d_out, out_size, val);
    return;
  }

  // ---- dtype detect + weight prep ----
  k_detect<<<1, 256, 0, stream>>>((const u32*)d_in[6], flag);
  const int mlp_tot = HDIM * HDIM;
  for (int j = 0; j < 3; ++j) {
    k_build_wt<<<(mlp_tot + 255) / 256, 256, 0, stream>>>(
        d_in[6 + 2 * j], d_in[6 + 2 * j], HDIM, HDIM, HDIM, WT_lmlp[j], flag);
    k_build_wt<<<(mlp_tot + 255) / 256, 256, 0, stream>>>(
        d_in[12 + 2 * j], d_in[12 + 2 * j], HDIM, HDIM, HDIM, WT_cmlp[j], flag);
  }
  k_build_wt<<<(512 * 384 + 255) / 256, 256, 0, stream>>>(
      d_in[18], d_in[19], 256, 384, 512, WT_l, flag);
  k_build_wt<<<(512 * 256 + 255) / 256, 256, 0, stream>>>(
      d_in[21], d_in[22], 128, 256, 512, WT_c, flag);
  k_any_to_f32<<<1, 256, 0, stream>>>(d_in[7],  Bf_lmlp[0], HDIM / 8, flag);
  k_any_to_f32<<<1, 256, 0, stream>>>(d_in[9],  Bf_lmlp[1], HDIM / 8, flag);
  k_any_to_f32<<<1, 256, 0, stream>>>(d_in[11], Bf_lmlp[2], HDIM / 8, flag);
  k_any_to_f32<<<1, 256, 0, stream>>>(d_in[13], Bf_cmlp[0], HDIM / 8, flag);
  k_any_to_f32<<<1, 256, 0, stream>>>(d_in[15], Bf_cmlp[1], HDIM / 8, flag);
  k_any_to_f32<<<1, 256, 0, stream>>>(d_in[17], Bf_cmlp[2], HDIM / 8, flag);
  k_any_to_f32<<<1, 256, 0, stream>>>(d_in[20], Bf_l, 512 / 8, flag);
  k_any_to_f32<<<1, 256, 0, stream>>>(d_in[23], Bf_c, 512 / 8, flag);

  // ---- CSR build ----
  const int gE = (E + 255) / 256;
  (void)hipMemsetAsync(deg1, 0, (size_t)C * 4, stream);
  (void)hipMemsetAsync(deg2, 0, (size_t)L * 4, stream);
  k_count<<<gE, 256, 0, stream>>>(epd, 0, E, deg1);
  k_count<<<gE, 256, 0, stream>>>(end_, 0, E, deg1);
  k_count<<<gE, 256, 0, stream>>>(eps, 0, E, deg2);
  k_count<<<gE, 256, 0, stream>>>(ens, V, E, deg2);
  {
    int nb = (C + 1023) / 1024;
    k_scan1<<<nb, 256, 0, stream>>>(deg1, inc, bsum, C);
    k_scan2<<<1, 256, 0, stream>>>(bsum, nb);
    k_scan3<<<(C + 255) / 256, 256, 0, stream>>>(inc, bsum, off1, cur1, C);
  }
  {
    int nb = (L + 1023) / 1024;
    k_scan1<<<nb, 256, 0, stream>>>(deg2, inc, bsum, L);
    k_scan2<<<1, 256, 0, stream>>>(bsum, nb);
    k_scan3<<<(L + 255) / 256, 256, 0, stream>>>(inc, bsum, off2, cur2, L);
  }
  k_fill<<<gE, 256, 0, stream>>>(epd, 0, eps, 0, E, cur1, vals1);
  k_fill<<<gE, 256, 0, stream>>>(end_, 0, ens, V, E, cur1, vals1);
  k_fill<<<gE, 256, 0, stream>>>(eps, 0, epd, 0, E, cur2, vals2);
  k_fill<<<gE, 256, 0, stream>>>(ens, V, end_, 0, E, cur2, vals2);

  // ---- init states (cell states start at 0 -> handled by FIRST template, no memset) ----
  k_any_to_bf16<<<(int)((LH / 8 + 255) / 256), 256, 0, stream>>>(l_emb, l_hA, (int)(LH / 8), flag);
  k_any_to_bf16<<<(int)((CH / 8 + 255) / 256), 256, 0, stream>>>(c_emb, c_h, (int)(CH / 8), flag);

  u16* lh_cur = l_hA;
  u16* lh_nxt = l_hB;
  float* outf = (float*)d_out;

  const int gm_l = (L + 127) / 128;
  const int gm_c = (C + 127) / 128;
  const int gs_c = (C + 63) / 64;
  const int gs_l = (L + 63) / 64;

  for (int r = 0; r < R; ++r) {
    // literal MLP3 -> tL, clause MLP3 -> tC
    k_mlp3<<<gm_l, 256, 0, stream>>>(lh_cur, tL, L,
        WT_lmlp[0], Bf_lmlp[0], WT_lmlp[1], Bf_lmlp[1], WT_lmlp[2], Bf_lmlp[2]);
    k_mlp3<<<gm_c, 256, 0, stream>>>(c_h, tC, C,
        WT_cmlp[0], Bf_cmlp[0], WT_cmlp[1], Bf_cmlp[1], WT_cmlp[2], Bf_cmlp[2]);
    // LSTMs with fused gather
    if (r == 0) {
      k_lstm3<0, 0, 1, 0><<<gs_c, 512, 0, stream>>>(
          tL, off1, vals1, (const u16*)nullptr, 0, c_h, c_c,
          (void*)c_h, c_c, WT_c, Bf_c, C);
      k_lstm3<1, 0, 1, 0><<<gs_l, 512, 0, stream>>>(
          tC, off2, vals2, lh_cur, V, lh_cur, l_c,
          (void*)lh_nxt, l_c, WT_l, Bf_l, L);
      u16* tmp = lh_cur; lh_cur = lh_nxt; lh_nxt = tmp;
    } else if (r == R - 1) {
      k_lstm3<0, 1, 0, 1><<<gs_c, 512, 0, stream>>>(
          tL, off1, vals1, (const u16*)nullptr, 0, c_h, c_c,
          (void*)(outf + LH), c_c, WT_c, Bf_c, C);
      k_lstm3<1, 1, 0, 1><<<gs_l, 512, 0, stream>>>(
          tC, off2, vals2, lh_cur, V, lh_cur, l_c,
          (void*)outf, l_c, WT_l, Bf_l, L);
    } else {
      k_lstm3<0, 0, 0, 0><<<gs_c, 512, 0, stream>>>(
          tL, off1, vals1, (const u16*)nullptr, 0, c_h, c_c,
          (void*)c_h, c_c, WT_c, Bf_c, C);
      k_lstm3<1, 0, 0, 0><<<gs_l, 512, 0, stream>>>(
          tC, off2, vals2, lh_cur, V, lh_cur, l_c,
          (void*)lh_nxt, l_c, WT_l, Bf_l, L);
      u16* tmp = lh_cur; lh_cur = lh_nxt; lh_nxt = tmp;
    }
  }
}